// Round 1
// baseline (2820.112 us; speedup 1.0000x reference)
//
#include <hip/hip_runtime.h>

// Problem constants (verified against setup_inputs): IN_CH=65, HID_CH=64.
#define IN_CH 65
#define HID 64

// ---------------------------------------------------------------------------
// prep_wt: build Wt[c][j] (c in [0,65), j in [0,128)) where
//   j <  64 : W_rel[j][c]      (feeds y = x @ W_rel.T)
//   j >= 64 : W_root[j-64][c]  (feeds out = x @ W_root.T + b_rel)
// c-major layout so k1 reads 32 consecutive j for a fixed c (wave-uniform).
// ---------------------------------------------------------------------------
__global__ __launch_bounds__(128) void prep_wt(const float* __restrict__ W_rel,
                                               const float* __restrict__ W_root,
                                               float* __restrict__ Wt) {
    const int j = threadIdx.x;  // 0..127
    const float* W = (j < HID) ? (W_rel + j * IN_CH) : (W_root + (j - HID) * IN_CH);
    for (int c = 0; c < IN_CH; ++c)
        Wt[c * 128 + j] = W[c];  // coalesced writes across j
}

// ---------------------------------------------------------------------------
// k1: per node n compute
//   y[n][0:64]  = x[n] . W_rel  (columns j=0..63 of Wt)
//   out[n][0:64]= x[n] . W_root + b_rel (columns j=64..127)
// Block = 256 thr = 4 waves over a 64-node tile; wave w handles j-slice
// [32w, 32w+32). x tile staged in LDS with stride 65 (odd -> conflict-free:
// bank = (lane + c) % 32, 2 lanes/bank which is free per m136).
// W reads are wave-uniform -> expect s_load_dwordx16 from L1s.
// ---------------------------------------------------------------------------
__global__ __launch_bounds__(256) void k1(const float* __restrict__ x,
                                          const float* __restrict__ Wt,
                                          const float* __restrict__ b_rel,
                                          float* __restrict__ y,
                                          float* __restrict__ out,
                                          int nNodes) {
    __shared__ float xt[64 * IN_CH];
    const int tid  = threadIdx.x;
    const int lane = tid & 63;
    const int wv   = __builtin_amdgcn_readfirstlane(tid >> 6);  // 0..3, uniform
    const long nodeBase = (long)blockIdx.x * 64;

    const int nValid = min(64, nNodes - (int)nodeBase);
    const int total  = nValid * IN_CH;
    const float* xsrc = x + nodeBase * IN_CH;  // block's rows are contiguous
    for (int i = tid; i < total; i += 256) xt[i] = xsrc[i];
    __syncthreads();

    if (lane >= nValid) return;  // only possible in the last block

    const int j0 = wv * 32;
    float acc[32];
#pragma unroll
    for (int k = 0; k < 32; ++k) acc[k] = 0.f;

    const float* xrow = xt + lane * IN_CH;
    for (int c = 0; c < IN_CH; ++c) {
        const float xc = xrow[c];             // ds_read_b32, conflict-free
        const float* wr = Wt + c * 128 + j0;  // wave-uniform -> s_load
#pragma unroll
        for (int k = 0; k < 32; ++k) acc[k] += xc * wr[k];
    }

    float* dstbase;
    if (j0 < HID) {
        dstbase = y + (nodeBase + lane) * HID + j0;
    } else {
        const int h0 = j0 - HID;
#pragma unroll
        for (int k = 0; k < 32; ++k) acc[k] += b_rel[h0 + k];
        dstbase = out + (nodeBase + lane) * HID + h0;
    }
#pragma unroll
    for (int k = 0; k < 32; k += 4) {
        float4 v = make_float4(acc[k], acc[k + 1], acc[k + 2], acc[k + 3]);
        *(float4*)(dstbase + k) = v;  // 16B-aligned: n*256B + k*4B (k%4==0, j0%32==0)
    }
}

// ---------------------------------------------------------------------------
// k2: scatter. 16 threads per edge; thread r gathers float4 r of y[src]
// (row = 256 B, 16B aligned) and does 4 native f32 atomic adds into out[dst].
// ---------------------------------------------------------------------------
__global__ __launch_bounds__(256) void k2(const int* __restrict__ ei,
                                          const float* __restrict__ ew,
                                          const float* __restrict__ y,
                                          float* __restrict__ out,
                                          int E) {
    const long t = (long)blockIdx.x * 256 + threadIdx.x;
    const long e = t >> 4;
    const int  r = (int)(t & 15);
    if (e >= E) return;
    const int src = ei[e];
    const int dst = ei[(long)E + e];
    const float w = ew[e];
    const float4 v = ((const float4*)y)[(size_t)src * 16 + r];
    float* o = out + (size_t)dst * HID + r * 4;
    unsafeAtomicAdd(o + 0, w * v.x);
    unsafeAtomicAdd(o + 1, w * v.y);
    unsafeAtomicAdd(o + 2, w * v.z);
    unsafeAtomicAdd(o + 3, w * v.w);
}

extern "C" void kernel_launch(void* const* d_in, const int* in_sizes, int n_in,
                              void* d_out, int out_size, void* d_ws, size_t ws_size,
                              hipStream_t stream) {
    const float* x      = (const float*)d_in[0];
    const int*   ei     = (const int*)d_in[1];   // [2, E] int32
    const float* ew     = (const float*)d_in[2];
    const float* W_rel  = (const float*)d_in[3];
    const float* b_rel  = (const float*)d_in[4];
    const float* W_root = (const float*)d_in[5];
    float* out = (float*)d_out;

    const int nNodes = in_sizes[0] / IN_CH;  // 100000
    const int E      = in_sizes[2];          // 3200000

    // ws layout: y [nNodes*64 f32] | Wt [65*128 f32]
    float* y  = (float*)d_ws;
    float* Wt = (float*)((char*)d_ws + (size_t)nNodes * HID * sizeof(float));

    prep_wt<<<1, 128, 0, stream>>>(W_rel, W_root, Wt);

    const int nb1 = (nNodes + 63) / 64;
    k1<<<nb1, 256, 0, stream>>>(x, Wt, b_rel, y, out, nNodes);

    const long thr2 = (long)E * 16;
    const int  nb2  = (int)((thr2 + 255) / 256);
    k2<<<nb2, 256, 0, stream>>>(ei, ew, y, out, E);
}

// Round 2
// 652.943 us; speedup vs baseline: 4.3191x; 4.3191x over previous
//
#include <hip/hip_runtime.h>

#define IN_CH 65
#define HID 64

static inline size_t align16(size_t v) { return (v + 15) & ~(size_t)15; }

// ---------------------------------------------------------------------------
// prep_wt: Wt[c][j], c in [0,65), j in [0,128): j<64 -> W_rel[j][c],
// j>=64 -> W_root[j-64][c]. c-major so GEMM reads 128 consecutive j per c.
// ---------------------------------------------------------------------------
__global__ __launch_bounds__(128) void prep_wt(const float* __restrict__ W_rel,
                                               const float* __restrict__ W_root,
                                               float* __restrict__ Wt) {
    const int j = threadIdx.x;  // 0..127
    const float* W = (j < HID) ? (W_rel + j * IN_CH) : (W_root + (j - HID) * IN_CH);
    for (int c = 0; c < IN_CH; ++c)
        Wt[c * 128 + j] = W[c];
}

// ---------------------------------------------------------------------------
// k1: register-tiled GEMM  [64 nodes x 65] @ [65 x 128] per block.
// Thread (tx=tid&15, ty=tid>>4) computes 4 rows x 8 cols.
// cols 0..63 -> y = x@W_rel.T ; cols 64..127 -> out = x@W_root.T + b_rel.
// LDS: xs stride-65 (odd -> conflict-free), ws row 128 (f4 reads, broadcast).
// ---------------------------------------------------------------------------
__global__ __launch_bounds__(256) void k1(const float* __restrict__ x,
                                          const float* __restrict__ Wt,
                                          const float* __restrict__ b_rel,
                                          float* __restrict__ y,
                                          float* __restrict__ out,
                                          int nNodes) {
    __shared__ float xs[64 * IN_CH];   // 16.6 KB
    __shared__ float ws[IN_CH * 128];  // 33.3 KB
    const int tid = threadIdx.x;
    const int tx = tid & 15;       // col group
    const int ty = tid >> 4;       // row group
    const long nodeBase = (long)blockIdx.x * 64;
    const int nValid = min(64, nNodes - (int)nodeBase);
    const int nx = nValid * IN_CH;

    const float* xsrc = x + nodeBase * IN_CH;
    for (int i = tid; i < 64 * IN_CH; i += 256) xs[i] = (i < nx) ? xsrc[i] : 0.f;
    for (int i = tid; i < IN_CH * 128; i += 256) ws[i] = Wt[i];
    __syncthreads();

    float acc[4][8];
#pragma unroll
    for (int i = 0; i < 4; ++i)
#pragma unroll
        for (int j = 0; j < 8; ++j) acc[i][j] = 0.f;

    const int r0 = ty * 4;
    const int c0 = tx * 8;
    for (int k = 0; k < IN_CH; ++k) {
        float a0 = xs[(r0 + 0) * IN_CH + k];
        float a1 = xs[(r0 + 1) * IN_CH + k];
        float a2 = xs[(r0 + 2) * IN_CH + k];
        float a3 = xs[(r0 + 3) * IN_CH + k];
        float4 b0 = *(const float4*)&ws[k * 128 + c0];
        float4 b1 = *(const float4*)&ws[k * 128 + c0 + 4];
        float bb[8] = {b0.x, b0.y, b0.z, b0.w, b1.x, b1.y, b1.z, b1.w};
        float aa[4] = {a0, a1, a2, a3};
#pragma unroll
        for (int i = 0; i < 4; ++i)
#pragma unroll
            for (int j = 0; j < 8; ++j) acc[i][j] += aa[i] * bb[j];
    }

    if (c0 >= HID) {  // root half: add bias once
        const int h0 = c0 - HID;
        float4 bb0 = *(const float4*)&b_rel[h0];
        float4 bb1 = *(const float4*)&b_rel[h0 + 4];
        float bv[8] = {bb0.x, bb0.y, bb0.z, bb0.w, bb1.x, bb1.y, bb1.z, bb1.w};
#pragma unroll
        for (int i = 0; i < 4; ++i)
#pragma unroll
            for (int j = 0; j < 8; ++j) acc[i][j] += bv[j];
    }

#pragma unroll
    for (int i = 0; i < 4; ++i) {
        const long node = nodeBase + r0 + i;
        if (node >= nNodes) break;
        float* dst = (c0 < HID) ? (y + node * HID + c0)
                                : (out + node * HID + (c0 - HID));
        *(float4*)(dst + 0) = make_float4(acc[i][0], acc[i][1], acc[i][2], acc[i][3]);
        *(float4*)(dst + 4) = make_float4(acc[i][4], acc[i][5], acc[i][6], acc[i][7]);
    }
}

// ---------------------------------------------------------------------------
// Counting sort by dst + per-node wave reduction (no payload atomics).
// ---------------------------------------------------------------------------
__global__ __launch_bounds__(256) void hist(const int* __restrict__ ei,
                                            int* __restrict__ deg, int E) {
    const long e = (long)blockIdx.x * 256 + threadIdx.x;
    if (e >= E) return;
    atomicAdd(&deg[ei[(long)E + e]], 1);
}

__global__ __launch_bounds__(256) void scan1(const int* __restrict__ deg,
                                             int* __restrict__ bs, int N) {
    __shared__ int s[256];
    const int tid = threadIdx.x;
    const long i = (long)blockIdx.x * 256 + tid;
    s[tid] = (i < N) ? deg[i] : 0;
    __syncthreads();
    for (int off = 128; off > 0; off >>= 1) {
        if (tid < off) s[tid] += s[tid + off];
        __syncthreads();
    }
    if (tid == 0) bs[blockIdx.x] = s[0];
}

__global__ __launch_bounds__(512) void scan2(int* __restrict__ bs, int nb) {
    __shared__ int s[512];
    const int tid = threadIdx.x;
    const int v = (tid < nb) ? bs[tid] : 0;
    s[tid] = v;
    __syncthreads();
    for (int off = 1; off < 512; off <<= 1) {
        int t = (tid >= off) ? s[tid - off] : 0;
        __syncthreads();
        s[tid] += t;
        __syncthreads();
    }
    if (tid < nb) bs[tid] = s[tid] - v;  // exclusive
}

__global__ __launch_bounds__(256) void scan3(const int* __restrict__ deg,
                                             const int* __restrict__ bs,
                                             int* __restrict__ offsets,
                                             int* __restrict__ pos, int N) {
    __shared__ int s[256];
    const int tid = threadIdx.x;
    const long i = (long)blockIdx.x * 256 + tid;
    const int d = (i < N) ? deg[i] : 0;
    s[tid] = d;
    __syncthreads();
    for (int off = 1; off < 256; off <<= 1) {
        int t = (tid >= off) ? s[tid - off] : 0;
        __syncthreads();
        s[tid] += t;
        __syncthreads();
    }
    const int o = bs[blockIdx.x] + s[tid] - d;  // exclusive + block offset
    if (i < N) {
        offsets[i] = o;
        pos[i] = o;
        if (i == N - 1) offsets[N] = o + d;
    }
}

__global__ __launch_bounds__(256) void scatter(const int* __restrict__ ei,
                                               const float* __restrict__ ew,
                                               int* __restrict__ pos,
                                               int2* __restrict__ pairs, int E) {
    const long e = (long)blockIdx.x * 256 + threadIdx.x;
    if (e >= E) return;
    const int dst = ei[(long)E + e];
    const int p = atomicAdd(&pos[dst], 1);
    pairs[p] = make_int2(ei[e], __float_as_int(ew[e]));
}

// One wave per node; lane = channel. 4-edge unrolled gather-reduce.
__global__ __launch_bounds__(256) void aggregate(const int2* __restrict__ pairs,
                                                 const int* __restrict__ offsets,
                                                 const float* __restrict__ y,
                                                 float* __restrict__ out, int N) {
    const int lane = threadIdx.x & 63;
    const int wv = threadIdx.x >> 6;
    const int n = blockIdx.x * 4 + wv;
    if (n >= N) return;
    const int beg = offsets[n];
    const int end = offsets[n + 1];
    float acc = 0.f;
    int k = beg;
    for (; k + 4 <= end; k += 4) {
        int2 p0 = pairs[k], p1 = pairs[k + 1], p2 = pairs[k + 2], p3 = pairs[k + 3];
        float v0 = y[(size_t)p0.x * HID + lane];
        float v1 = y[(size_t)p1.x * HID + lane];
        float v2 = y[(size_t)p2.x * HID + lane];
        float v3 = y[(size_t)p3.x * HID + lane];
        acc += __int_as_float(p0.y) * v0;
        acc += __int_as_float(p1.y) * v1;
        acc += __int_as_float(p2.y) * v2;
        acc += __int_as_float(p3.y) * v3;
    }
    for (; k < end; ++k) {
        int2 p = pairs[k];
        acc += __int_as_float(p.y) * y[(size_t)p.x * HID + lane];
    }
    out[(size_t)n * HID + lane] += acc;  // out has root+bias from k1; wave owns row
}

// Fallback (R1 path) if ws too small: 16 thr/edge atomic scatter.
__global__ __launch_bounds__(256) void k2_atomic(const int* __restrict__ ei,
                                                 const float* __restrict__ ew,
                                                 const float* __restrict__ y,
                                                 float* __restrict__ out, int E) {
    const long t = (long)blockIdx.x * 256 + threadIdx.x;
    const long e = t >> 4;
    const int r = (int)(t & 15);
    if (e >= E) return;
    const int src = ei[e];
    const int dst = ei[(long)E + e];
    const float w = ew[e];
    const float4 v = ((const float4*)y)[(size_t)src * 16 + r];
    float* o = out + (size_t)dst * HID + r * 4;
    unsafeAtomicAdd(o + 0, w * v.x);
    unsafeAtomicAdd(o + 1, w * v.y);
    unsafeAtomicAdd(o + 2, w * v.z);
    unsafeAtomicAdd(o + 3, w * v.w);
}

extern "C" void kernel_launch(void* const* d_in, const int* in_sizes, int n_in,
                              void* d_out, int out_size, void* d_ws, size_t ws_size,
                              hipStream_t stream) {
    const float* x      = (const float*)d_in[0];
    const int*   ei     = (const int*)d_in[1];
    const float* ew     = (const float*)d_in[2];
    const float* W_rel  = (const float*)d_in[3];
    const float* b_rel  = (const float*)d_in[4];
    const float* W_root = (const float*)d_in[5];
    float* out = (float*)d_out;

    const int N = in_sizes[0] / IN_CH;  // 100000
    const int E = in_sizes[2];          // 3200000

    const int nbScan = (N + 255) / 256;  // 391 (must be <= 512 for scan2)

    // ws layout
    char* base = (char*)d_ws;
    const size_t oY     = 0;
    const size_t oPairs = align16((size_t)N * HID * 4);
    const size_t oDeg   = oPairs + align16((size_t)E * 8);
    const size_t oOff   = oDeg + align16((size_t)N * 4);
    const size_t oBS    = oOff + align16((size_t)(N + 1) * 4);
    const size_t oWt    = oBS + align16((size_t)nbScan * 4);
    const size_t need   = oWt + (size_t)IN_CH * 128 * 4;

    float* y = (float*)(base + oY);

    if (ws_size >= need && nbScan <= 512) {
        int2*  pairs   = (int2*)(base + oPairs);
        int*   deg     = (int*)(base + oDeg);
        int*   offsets = (int*)(base + oOff);
        int*   pos     = offsets;  // placeholder, real pos below
        int*   bs      = (int*)(base + oBS);
        float* Wt      = (float*)(base + oWt);
        // pos shares deg's buffer after scan3 consumed deg? No: scan3 reads deg
        // and writes pos — keep them separate: reuse deg as pos is unsafe
        // (scan3 reads deg[i] then writes pos[i]=o; same index, read-before-write
        // within thread — actually safe). Use deg as cursor after scan3.
        pos = deg;  // scan3 reads deg[i] into d first, then we overwrite via pos

        prep_wt<<<1, 128, 0, stream>>>(W_rel, W_root, Wt);
        k1<<<(N + 63) / 64, 256, 0, stream>>>(x, Wt, b_rel, y, out, N);

        hipMemsetAsync(deg, 0, (size_t)N * 4, stream);
        hist<<<(E + 255) / 256, 256, 0, stream>>>(ei, deg, E);
        scan1<<<nbScan, 256, 0, stream>>>(deg, bs, N);
        scan2<<<1, 512, 0, stream>>>(bs, nbScan);
        scan3<<<nbScan, 256, 0, stream>>>(deg, bs, offsets, pos, N);
        scatter<<<(E + 255) / 256, 256, 0, stream>>>(ei, ew, pos, pairs, E);
        aggregate<<<(N + 3) / 4, 256, 0, stream>>>(pairs, offsets, y, out, N);
    } else {
        // fallback: R1 layout (y + Wt only)
        float* Wt = (float*)(base + align16((size_t)N * HID * 4));
        prep_wt<<<1, 128, 0, stream>>>(W_rel, W_root, Wt);
        k1<<<(N + 63) / 64, 256, 0, stream>>>(x, Wt, b_rel, y, out, N);
        const long thr2 = (long)E * 16;
        k2_atomic<<<(int)((thr2 + 255) / 256), 256, 0, stream>>>(ei, ew, y, out, E);
    }
}